// Round 3
// baseline (635.127 us; speedup 1.0000x reference)
//
#include <hip/hip_runtime.h>
#include <math.h>

// Problem constants (B=8, H=W=128, C=128, R=4 -> 81 cost channels)
#define BATCH 8
#define HH 128
#define WW 128
#define CC 128
#define RR 4
#define DDIM 9
#define NS 81
#define NSP 96          // cost channels padded to 96 (zero-filled 81..95)
#define HWPIX (HH*WW)
#define DSLAB 1032      // dsh slab stride in shorts (1024 + 8: kills 4-way write conflicts)

typedef short  short8  __attribute__((ext_vector_type(8)));
typedef float  f32x4   __attribute__((ext_vector_type(4)));

__device__ __forceinline__ short bf16h(float f){
    unsigned u = __float_as_uint(f);
    u += 0x7fffu + ((u >> 16) & 1u);
    return (short)(u >> 16);
}
__device__ __forceinline__ float bf16f(short s){
    return __uint_as_float(((unsigned)(unsigned short)s) << 16);
}
__device__ __forceinline__ float mish_f(float x){
    float xc = fminf(x, 30.f);
    float t = expf(xc);
    float u = t*t + 2.f*t;
    return x * (u / (u + 2.f));
}

// async global->LDS DMA, 16 B/lane.  LDS dest = first-active-lane base +
// lane*16 => prefix-only masking, OOB lanes read a zero-scratch global addr.
__device__ __forceinline__ void gld16(float* lds, const float* g){
    __builtin_amdgcn_global_load_lds(
        (const __attribute__((address_space(1))) unsigned int*)g,
        (__attribute__((address_space(3))) unsigned int*)lds, 16, 0, 0);
}

// LDS-only barrier: orders ds_write/ds_read without draining vmcnt, so
// in-flight prefetch DMA keeps flying across it.
__device__ __forceinline__ void lds_barrier(){
    __asm volatile("s_waitcnt lgkmcnt(0)\n\ts_barrier" ::: "memory");
}

__global__ void zero_k(float* p, int n){
    int i = blockIdx.x*256 + threadIdx.x;
    if(i < n) p[i] = 0.f;
}

// ---------------------------------------------------------------------------
// Cost volume: 16x16 px tile, 128 threads, 2 vertically-adjacent px/thread.
// The two 9x9 search windows share rows: union 10x9 -> per-px LDS reads drop
// 162 -> 90 per chunk (kernel was LDS-read-pipe bound at ~4 B/FMA).
// nxt halo in q-plane-major float4 slots [q][row24][col24]: DMA dest stays
// exactly lane-linear (addr = 16*e), quarter-wave reads are uniform
// 2 words/bank.  Double-buffered; next chunk's DMA + prv reg prefetch issued
// right after the per-chunk barrier (overlapped by the 1296-FMA compute).
// ---------------------------------------------------------------------------
__global__ __launch_bounds__(128,2) void cost_kernel(
    const float* __restrict__ prv, const float* __restrict__ nxt,
    const float* __restrict__ zb, float* __restrict__ cost)
{
    __shared__ float nx[2][1152*4];     // 2 q-planes x 576 slots x float4
    const int tid = threadIdx.x;
    const int tx = tid & 15, ty = tid >> 4;          // ty 0..7
    const int x0 = blockIdx.x*16, y0 = blockIdx.y*16, b = blockIdx.z;
    const int yA = y0 + 2*ty;                        // this thread's 2 rows

    float acc0[NS], acc1[NS];
#pragma unroll
    for(int s=0;s<NS;s++){ acc0[s]=0.f; acc1[s]=0.f; }

    const float* prvA = prv + (((size_t)b*HH + yA)*WW + (x0+tx))*CC;
    const float* prvB = prvA + (size_t)WW*CC;
    const float* nxb  = nxt + (size_t)b*HH*WW*CC;

    auto stagec = [&](int c0, int pb){
        float* xp = &nx[pb][0];
#pragma unroll
        for(int it=0;it<9;it++){
            int e = it*128 + tid;                    // e < 1152, all active
            int q = (e >= 576) ? 1 : 0;
            int p = e - q*576;
            int row = p/24, col = p - row*24;
            int hy = y0 - RR + row, hx = x0 - RR + col;
            bool ok = hy>=0 && hy<HH && hx>=0 && hx<WW;
            const float* gp = ok ? (nxb + ((size_t)hy*WW + hx)*CC + c0 + q*4)
                                 : zb;
            gld16(xp + e*4, gp);
        }
    };

    float4 pA0r = *(const float4*)(prvA);
    float4 pB0r = *(const float4*)(prvA + 4);
    float4 pA1r = *(const float4*)(prvB);
    float4 pB1r = *(const float4*)(prvB + 4);
    stagec(0, 0);
    int pb = 0;
    for(int c0=0;c0<CC;c0+=8){
        __syncthreads();              // drains DMA for this chunk (+ prv regs)
        float4 A0 = pA0r, B0 = pB0r, A1 = pA1r, B1 = pB1r;
        if(c0+8 < CC){
            pA0r = *(const float4*)(prvA + c0 + 8);  // plain loads first...
            pB0r = *(const float4*)(prvA + c0 + 12);
            pA1r = *(const float4*)(prvB + c0 + 8);
            pB1r = *(const float4*)(prvB + c0 + 12);
            stagec(c0+8, pb^1);                      // ...then prefetch DMA
        }
        const float* xp = &nx[pb][0];
#pragma unroll
        for(int i=0;i<10;i++){                       // union window rows
            const float* rp = xp + (((2*ty + i)*24) + tx)*4;
#pragma unroll
            for(int j=0;j<DDIM;j++){
                float4 n0 = *(const float4*)(rp + j*4);
                float4 n1 = *(const float4*)(rp + j*4 + 2304);  // q1 plane
                if(i < 9){
                    float s = acc0[i*DDIM+j];
                    s = fmaf(A0.x,n0.x,s);  s = fmaf(A0.y,n0.y,s);
                    s = fmaf(A0.z,n0.z,s);  s = fmaf(A0.w,n0.w,s);
                    s = fmaf(B0.x,n1.x,s);  s = fmaf(B0.y,n1.y,s);
                    s = fmaf(B0.z,n1.z,s);  s = fmaf(B0.w,n1.w,s);
                    acc0[i*DDIM+j] = s;
                }
                if(i > 0){
                    float s = acc1[(i-1)*DDIM+j];
                    s = fmaf(A1.x,n0.x,s);  s = fmaf(A1.y,n0.y,s);
                    s = fmaf(A1.z,n0.z,s);  s = fmaf(A1.w,n0.w,s);
                    s = fmaf(B1.x,n1.x,s);  s = fmaf(B1.y,n1.y,s);
                    s = fmaf(B1.z,n1.z,s);  s = fmaf(B1.w,n1.w,s);
                    acc1[(i-1)*DDIM+j] = s;
                }
            }
        }
        pb ^= 1;
    }
    float* opA = cost + (((size_t)b*HH + yA)*WW + (x0+tx))*NSP;
    float* opB = opA + (size_t)WW*NSP;
#pragma unroll
    for(int g=0; g<NSP/4; g++){
        int s = g*4;
        float4 v0, v1;
        v0.x = (s   < NS) ? acc0[s  ]*(1.f/128.f) : 0.f;
        v0.y = (s+1 < NS) ? acc0[s+1]*(1.f/128.f) : 0.f;
        v0.z = (s+2 < NS) ? acc0[s+2]*(1.f/128.f) : 0.f;
        v0.w = (s+3 < NS) ? acc0[s+3]*(1.f/128.f) : 0.f;
        v1.x = (s   < NS) ? acc1[s  ]*(1.f/128.f) : 0.f;
        v1.y = (s+1 < NS) ? acc1[s+1]*(1.f/128.f) : 0.f;
        v1.z = (s+2 < NS) ? acc1[s+2]*(1.f/128.f) : 0.f;
        v1.w = (s+3 < NS) ? acc1[s+3]*(1.f/128.f) : 0.f;
        *(float4*)(opA + s) = v0;
        *(float4*)(opB + s) = v1;
    }
}

// ---------------------------------------------------------------------------
// Pointwise weight prep (hi/lo bf16 B-fragment slabs), remap for padded concat.
// ---------------------------------------------------------------------------
__global__ void prep_pw(const float* __restrict__ src, short* __restrict__ dh,
                        short* __restrict__ dl, int K, int N, int NP, int total,
                        int remap)
{
    int idx = blockIdx.x*256 + threadIdx.x;
    if(idx >= total) return;
    int j  = idx & 7;
    int n  = (idx>>3) % NP;
    int k8 = (idx>>3) / NP;
    int k  = k8*8 + j;
    if(remap) k = (k < 81) ? k : ((k < 96) ? -1 : k - 15);
    float v = (k>=0 && k<K && n<N) ? src[(size_t)k*N + n] : 0.f;
    short h = bf16h(v);
    dh[idx] = h;
    dl[idx] = bf16h(v - bf16f(h));
}

// Depthwise weight prep: [9][K0] slab, remapped/zero-padded.
__global__ void prep_dw(const float* __restrict__ src, float* __restrict__ dst,
                        int K, int K0, int remap, int total)
{
    int idx = blockIdx.x*256 + threadIdx.x;
    if(idx >= total) return;
    int k = idx / K0, c = idx - k*K0;
    int cr = c;
    if(remap) cr = (c < 81) ? c : ((c < 96) ? -1 : c - 15);
    dst[idx] = (cr>=0 && cr<K) ? src[k*K + cr] : 0.f;
}

// ---------------------------------------------------------------------------
// Fused depthwise-3x3 (fp32 VALU) + pointwise-1x1 (split-bf16 MFMA, fp32 acc).
// Tile 16x8 px, 4 waves 2(m)x2(n).  K-chunks of 32, double-buffered DMA
// staging; chunk k+1's DMA issued after chunk k's opening barrier (overlaps
// depthwise+MFMA of chunk k); lgkm-only mid barrier keeps the prefetch
// in flight through the MFMA phase.
//
// Depthwise work grouping: one thread = 4 horizontally-consecutive px x 4 ch.
// The 3x3 window over 4 px spans 3 rows x 6 cols -> 18 xv reads (was 36) and
// 9 weight reads (was 36) per chunk.  dsh slab stride = DSLAB=1032 shorts so
// the hi/lo b64 writes land on 16 distinct bank-pair columns per 16 lanes.
// ---------------------------------------------------------------------------
template<int CINR,int K0,int COUT,int NP,bool BIAS,bool ACT,bool CONCAT>
__global__ __launch_bounds__(256,2) void sep_mfma(
    const float* __restrict__ xin, const float* __restrict__ cost,
    const float* __restrict__ prv, const float* __restrict__ nxt,
    const float* __restrict__ dwp, const short* __restrict__ wh,
    const short* __restrict__ wl, const float* __restrict__ bias,
    const float* __restrict__ zb, float* __restrict__ out)
{
    constexpr int TN = NP/32;           // n-tiles per wave (16 couts each)
    __shared__ float xs[2][180*36];     // halo 10(y) x 18(x), stride 36
    __shared__ short dshh[4*DSLAB];     // [k8][px][j]  hi
    __shared__ short dshl[4*DSLAB];     // [k8][px][j]  lo
    __shared__ float dwls[2][9*32];

    const int tid = threadIdx.x;
    const int x0 = blockIdx.x*16, y0 = blockIdx.y*8, b = blockIdx.z;
    const int lane = tid & 63;
    const int wv   = tid >> 6;
    const int wm   = wv >> 1, wn = wv & 1;
    const int l15  = lane & 15, quad = lane >> 4;

    f32x4 acc[4][TN];
#pragma unroll
    for(int i=0;i<4;i++)
#pragma unroll
        for(int nt=0;nt<TN;nt++) acc[i][nt] = (f32x4){0.f,0.f,0.f,0.f};

    auto stage = [&](int c0, int pb){
        if(tid < 72)
            gld16(&dwls[pb][(tid>>3)*32 + (tid&7)*4],
                  dwp + (tid>>3)*K0 + c0 + (tid&7)*4);
        const float* src; int str, coff;
        if(CONCAT){
            if(c0 < 96)      { src = cost; str = NSP; coff = c0; }
            else if(c0 < 224){ src = prv;  str = 128; coff = c0-96; }
            else             { src = nxt;  str = 128; coff = c0-224; }
        } else { src = xin; str = CINR; coff = c0; }
        const float* sb = src + (size_t)b*HH*WW*str + coff;
        float* xp = &xs[pb][0];
#pragma unroll
        for(int it=0;it<7;it++){
            int e = it*256 + tid;
            if(e < 1620){                               // prefix mask only
                int hp = e/9, q = e - hp*9;
                int hy = y0-1 + hp/18, hx = x0-1 + hp%18;
                bool ok = (q < 8) && hy>=0 && hy<HH && hx>=0 && hx<WW;
                const float* gp = ok ? (sb + ((size_t)hy*WW + hx)*str + q*4)
                                     : zb;
                gld16(xp + hp*36 + q*4, gp);
            }
        }
    };

    // depthwise work identity: 4 consecutive px (same row), 4 channels
    const int c4  = tid & 7;           // channel quartet 0..7
    const int pxg = tid >> 3;          // pixel group 0..31
    const int dpy = pxg >> 2;          // tile row 0..7
    const int dxb = (pxg & 3) * 4;     // tile col base 0,4,8,12

    stage(0, 0);
    int pb = 0;
    for(int c0=0;c0<K0;c0+=32){
        __syncthreads();   // drains this chunk's DMA (issued last iteration)
        // ---- B fragments for this chunk (issued before prefetch DMA) ----
        const int k8 = (c0>>3) + quad;
        short8 Bh[TN], Bl[TN];
#pragma unroll
        for(int nt=0;nt<TN;nt++){
            int n = wn*(NP/2) + nt*16 + l15;
            size_t off = ((size_t)k8*NP + n)*8;
            Bh[nt] = *(const short8*)(wh + off);
            Bl[nt] = *(const short8*)(wl + off);
        }
        // ---- prefetch next chunk into the other buffer ----
        if(c0+32 < K0) stage(c0+32, pb^1);
        // ---- depthwise 3x3: 4 px x 4 ch per thread, sliding 6-col window ----
        const float* xp = &xs[pb][0];
        const float* dwc = &dwls[pb][0];
        {
            float4 o[4];
#pragma unroll
            for(int dx=0;dx<4;dx++) o[dx] = make_float4(0.f,0.f,0.f,0.f);
#pragma unroll
            for(int kh=0;kh<3;kh++){
                float4 xw[6];
#pragma unroll
                for(int t=0;t<6;t++)
                    xw[t] = *(const float4*)&xp[((dpy+kh)*18 + dxb + t)*36 + c4*4];
#pragma unroll
                for(int kw=0;kw<3;kw++){
                    float4 w4 = *(const float4*)&dwc[(kh*3+kw)*32 + c4*4];
#pragma unroll
                    for(int dx=0;dx<4;dx++){
                        float4 xv = xw[kw+dx];
                        o[dx].x = fmaf(xv.x,w4.x,o[dx].x);
                        o[dx].y = fmaf(xv.y,w4.y,o[dx].y);
                        o[dx].z = fmaf(xv.z,w4.z,o[dx].z);
                        o[dx].w = fmaf(xv.w,w4.w,o[dx].w);
                    }
                }
            }
            const int wbase = (c4>>1)*DSLAB + (pxg*4)*8 + (c4&1)*4;
#pragma unroll
            for(int dx=0;dx<4;dx++){
                float4 s = o[dx];
                short h0=bf16h(s.x), h1=bf16h(s.y), h2=bf16h(s.z), h3=bf16h(s.w);
                short l0=bf16h(s.x-bf16f(h0)), l1=bf16h(s.y-bf16f(h1));
                short l2=bf16h(s.z-bf16f(h2)), l3=bf16h(s.w-bf16f(h3));
                *(short4*)&dshh[wbase + dx*8] = make_short4(h0,h1,h2,h3);
                *(short4*)&dshl[wbase + dx*8] = make_short4(l0,l1,l2,l3);
            }
        }
        lds_barrier();     // orders dsh writes/reads; DMA keeps flying
        // ---- MFMA: A from LDS, B from registers ----
#pragma unroll
        for(int i=0;i<4;i++){
            int ab = quad*DSLAB + (wm*64 + i*16 + l15)*8;
            short8 Ah = *(const short8*)&dshh[ab];
            short8 Al = *(const short8*)&dshl[ab];
#pragma unroll
            for(int nt=0;nt<TN;nt++){
                f32x4 c = acc[i][nt];
                c = __builtin_amdgcn_mfma_f32_16x16x32_bf16(Ah,Bh[nt],c,0,0,0);
                c = __builtin_amdgcn_mfma_f32_16x16x32_bf16(Al,Bh[nt],c,0,0,0);
                c = __builtin_amdgcn_mfma_f32_16x16x32_bf16(Ah,Bl[nt],c,0,0,0);
                acc[i][nt] = c;
            }
        }
        lds_barrier();     // dsh reads done before next chunk's dw writes
        pb ^= 1;
    }
    // ---- epilogue: bias + mish + store ----
#pragma unroll
    for(int i=0;i<4;i++){
        int pxb = wm*64 + i*16 + quad*4;
#pragma unroll
        for(int nt=0;nt<TN;nt++){
            int cout = wn*(NP/2) + nt*16 + l15;
            if(cout < COUT){
                float bv = BIAS ? bias[cout] : 0.f;
#pragma unroll
                for(int r=0;r<4;r++){
                    int p = pxb + r;
                    int y = y0 + (p>>4), x = x0 + (p&15);
                    float v = acc[i][nt][r] + bv;
                    if(ACT) v = mish_f(v);
                    out[(((size_t)b*HH + y)*WW + x)*COUT + cout] = v;
                }
            }
        }
    }
}

// ---------------------------------------------------------------------------
extern "C" void kernel_launch(void* const* d_in, const int* in_sizes, int n_in,
                              void* d_out, int out_size, void* d_ws, size_t ws_size,
                              hipStream_t stream)
{
    (void)in_sizes; (void)n_in; (void)out_size;
    const float* prv = (const float*)d_in[0];
    const float* nxt = (const float*)d_in[1];
    const float* dws[6] = {(const float*)d_in[2],(const float*)d_in[5],(const float*)d_in[8],
                           (const float*)d_in[11],(const float*)d_in[14],(const float*)d_in[17]};
    const float* pws[6] = {(const float*)d_in[3],(const float*)d_in[6],(const float*)d_in[9],
                           (const float*)d_in[12],(const float*)d_in[15],(const float*)d_in[18]};
    const float* b0  = (const float*)d_in[4];
    const float* b1  = (const float*)d_in[7];
    const float* b2  = (const float*)d_in[10];
    const float* b3  = (const float*)d_in[13];
    const float* b4  = (const float*)d_in[16];

    // ---- weight slabs: pw hi/lo bf16 + dw fp32 [9][K0] + zero scratch ----
    const int   Ks[6]   = {337,128,128, 96, 64, 32};
    const int   K0s[6]  = {352,128,128, 96, 64, 32};
    const int   Ns[6]   = {128,128, 96, 64, 32,  2};
    const int   NPs[6]  = {128,128, 96, 64, 32, 32};
    const int   rmp[6]  = {  1,  0,  0,  0,  0,  0};
    size_t offs[6]; size_t E = 0;
    for(int i=0;i<6;i++){ offs[i] = E; E += (size_t)K0s[i]*NPs[i]; }
    size_t dwoffs[6]; size_t Edw = 0;
    for(int i=0;i<6;i++){ dwoffs[i] = Edw; Edw += (size_t)9*K0s[i]; }

    short* Whs = (short*)d_ws;
    short* Wls = Whs + E;
    float* Dwp = (float*)((char*)d_ws + ((E*2*sizeof(short) + 255) & ~(size_t)255));
    float* Zb  = Dwp + Edw;                    // 64-float zero scratch
    size_t wbytes = (((char*)(Zb + 64) - (char*)d_ws) + 255) & ~(size_t)255;

    zero_k<<<1,64,0,stream>>>(Zb, 64);
    for(int i=0;i<6;i++){
        int total = K0s[i]*NPs[i];
        prep_pw<<<(total+255)/256,256,0,stream>>>(pws[i], Whs+offs[i], Wls+offs[i],
                                                  Ks[i], Ns[i], NPs[i], total, rmp[i]);
        int tdw = 9*K0s[i];
        prep_dw<<<(tdw+255)/256,256,0,stream>>>(dws[i], Dwp+dwoffs[i],
                                                Ks[i], K0s[i], rmp[i], tdw);
    }

    // ---- activation buffers, batch-chunked ----
    const size_t per_batch_floats = (size_t)HWPIX * (NSP + 128 + 128);
    size_t avail = (ws_size > wbytes) ? (ws_size - wbytes) : 0;
    int NB = (int)(avail / (per_batch_floats * sizeof(float)));
    if(NB > BATCH) NB = BATCH;
    if(NB < 1)     NB = 1;
    while(BATCH % NB) NB--;

    float* fbase = (float*)((char*)d_ws + wbytes);
    float* costb = fbase;
    float* bufA  = costb + (size_t)NB*HWPIX*NSP;
    float* bufB  = bufA  + (size_t)NB*HWPIX*128;

    for(int bb=0; bb<BATCH; bb+=NB){
        const float* prv_o = prv + (size_t)bb*HWPIX*CC;
        const float* nxt_o = nxt + (size_t)bb*HWPIX*CC;
        float*       out_o = (float*)d_out + (size_t)bb*HWPIX*2;
        dim3 gc(WW/16, HH/16, NB);
        dim3 gs(WW/16, HH/8,  NB);

        cost_kernel<<<gc,128,0,stream>>>(prv_o, nxt_o, Zb, costb);
        sep_mfma<337,352,128,128,true ,true ,true ><<<gs,256,0,stream>>>(nullptr, costb, prv_o, nxt_o, Dwp+dwoffs[0], Whs+offs[0], Wls+offs[0], b0, Zb, bufA);
        sep_mfma<128,128,128,128,true ,true ,false><<<gs,256,0,stream>>>(bufA, nullptr,nullptr,nullptr, Dwp+dwoffs[1], Whs+offs[1], Wls+offs[1], b1, Zb, bufB);
        sep_mfma<128,128, 96, 96,true ,true ,false><<<gs,256,0,stream>>>(bufB, nullptr,nullptr,nullptr, Dwp+dwoffs[2], Whs+offs[2], Wls+offs[2], b2, Zb, bufA);
        sep_mfma< 96, 96, 64, 64,true ,true ,false><<<gs,256,0,stream>>>(bufA, nullptr,nullptr,nullptr, Dwp+dwoffs[3], Whs+offs[3], Wls+offs[3], b3, Zb, bufB);
        sep_mfma< 64, 64, 32, 32,true ,true ,false><<<gs,256,0,stream>>>(bufB, nullptr,nullptr,nullptr, Dwp+dwoffs[4], Whs+offs[4], Wls+offs[4], b4, Zb, bufA);
        sep_mfma< 32, 32,  2, 32,false,false,false><<<gs,256,0,stream>>>(bufA, nullptr,nullptr,nullptr, Dwp+dwoffs[5], Whs+offs[5], Wls+offs[5], nullptr, Zb, out_o);
    }
}

// Round 4
// 576.901 us; speedup vs baseline: 1.1009x; 1.1009x over previous
//
#include <hip/hip_runtime.h>
#include <math.h>

// Problem constants (B=8, H=W=128, C=128, R=4 -> 81 cost channels)
#define BATCH 8
#define HH 128
#define WW 128
#define CC 128
#define RR 4
#define DDIM 9
#define NS 81
#define NSP 96          // cost channels padded to 96 (zero-filled 81..95)
#define HWPIX (HH*WW)
#define DSLAB 1032      // dsh slab stride in shorts (1024 + 8: kills 4-way write conflicts)

typedef short  short8  __attribute__((ext_vector_type(8)));
typedef float  f32x4   __attribute__((ext_vector_type(4)));

__device__ __forceinline__ short bf16h(float f){
    unsigned u = __float_as_uint(f);
    u += 0x7fffu + ((u >> 16) & 1u);
    return (short)(u >> 16);
}
__device__ __forceinline__ float bf16f(short s){
    return __uint_as_float(((unsigned)(unsigned short)s) << 16);
}
__device__ __forceinline__ float mish_f(float x){
    float xc = fminf(x, 30.f);
    float t = expf(xc);
    float u = t*t + 2.f*t;
    return x * (u / (u + 2.f));
}

// async global->LDS DMA, 16 B/lane.  LDS dest = first-active-lane base +
// lane*16 => prefix-only masking, OOB lanes read a zero-scratch global addr.
__device__ __forceinline__ void gld16(float* lds, const float* g){
    __builtin_amdgcn_global_load_lds(
        (const __attribute__((address_space(1))) unsigned int*)g,
        (__attribute__((address_space(3))) unsigned int*)lds, 16, 0, 0);
}

// LDS-only barrier: orders ds_write/ds_read without draining vmcnt, so
// in-flight prefetch DMA keeps flying across it.
__device__ __forceinline__ void lds_barrier(){
    __asm volatile("s_waitcnt lgkmcnt(0)\n\ts_barrier" ::: "memory");
}

__global__ void zero_k(float* p, int n){
    int i = blockIdx.x*256 + threadIdx.x;
    if(i < n) p[i] = 0.f;
}

// ---------------------------------------------------------------------------
// Cost volume: 16x16 px tile, 256 threads, 1 px/thread (8 waves/CU occupancy
// -- the 2px/thread variant halved wave count to 1/SIMD and regressed).
// nxt halo staged in q-plane-major float4 slots [q][row24*24+col24]: DMA dest
// lane-linear (addr = 16*e, zero pad-loads eliminated: 1152 DMAs vs 1728),
// and the window reads are conflict-free (measured 0 conflicts in r3):
// quarter-wave lanes read 16 consecutive float4 slots -> 2 dwords/bank.
// Double-buffered; next chunk's DMA + prv reg prefetch issued right after the
// per-chunk barrier (overlapped by the 648-FMA compute phase).
// ---------------------------------------------------------------------------
__global__ __launch_bounds__(256,2) void cost_kernel(
    const float* __restrict__ prv, const float* __restrict__ nxt,
    const float* __restrict__ zb, float* __restrict__ cost)
{
    __shared__ float nx[2][2304*2];     // 2 q-planes x 576 slots x float4
    const int tid = threadIdx.x;
    const int tx = tid & 15, ty = tid >> 4;
    const int x0 = blockIdx.x*16, y0 = blockIdx.y*16, b = blockIdx.z;

    float acc[NS];
#pragma unroll
    for(int s=0;s<NS;s++) acc[s]=0.f;

    const float* prvp = prv + (((size_t)b*HH + (y0+ty))*WW + (x0+tx))*CC;
    const float* nxb  = nxt + (size_t)b*HH*WW*CC;

    auto stagec = [&](int c0, int pb){
        float* xp = &nx[pb][0];
#pragma unroll
        for(int it=0;it<5;it++){
            int e = it*256 + tid;
            if(e < 1152){                               // prefix mask only
                int q = (e >= 576) ? 1 : 0;
                int p = e - q*576;
                int row = p/24, col = p - row*24;
                int hy = y0 - RR + row, hx = x0 - RR + col;
                bool ok = hy>=0 && hy<HH && hx>=0 && hx<WW;
                const float* gp = ok ? (nxb + ((size_t)hy*WW + hx)*CC + c0 + q*4)
                                     : zb;
                gld16(xp + e*4, gp);
            }
        }
    };

    float4 pAr = *(const float4*)(prvp);
    float4 pBr = *(const float4*)(prvp + 4);
    stagec(0, 0);
    int pb = 0;
    for(int c0=0;c0<CC;c0+=8){
        __syncthreads();              // drains DMA for this chunk (+ prv regs)
        float4 A = pAr, Bv = pBr;
        if(c0+8 < CC){
            pAr = *(const float4*)(prvp + c0 + 8);   // plain loads first...
            pBr = *(const float4*)(prvp + c0 + 12);
            stagec(c0+8, pb^1);                      // ...then prefetch DMA
        }
        const float* xp = &nx[pb][0];
#pragma unroll
        for(int i=0;i<DDIM;i++){
            const float* rp = xp + (((ty+i)*24 + tx))*4;
#pragma unroll
            for(int j=0;j<DDIM;j++){
                float4 n0 = *(const float4*)(rp + j*4);
                float4 n1 = *(const float4*)(rp + j*4 + 2304);  // q1 plane
                float s = acc[i*DDIM+j];
                s = fmaf(A.x,n0.x,s);  s = fmaf(A.y,n0.y,s);
                s = fmaf(A.z,n0.z,s);  s = fmaf(A.w,n0.w,s);
                s = fmaf(Bv.x,n1.x,s); s = fmaf(Bv.y,n1.y,s);
                s = fmaf(Bv.z,n1.z,s); s = fmaf(Bv.w,n1.w,s);
                acc[i*DDIM+j] = s;
            }
        }
        pb ^= 1;
    }
    float* op = cost + (((size_t)b*HH + (y0+ty))*WW + (x0+tx))*NSP;
#pragma unroll
    for(int g=0; g<NSP/4; g++){
        float4 v;
        int s = g*4;
        v.x = (s   < NS) ? acc[s  ]*(1.f/128.f) : 0.f;
        v.y = (s+1 < NS) ? acc[s+1]*(1.f/128.f) : 0.f;
        v.z = (s+2 < NS) ? acc[s+2]*(1.f/128.f) : 0.f;
        v.w = (s+3 < NS) ? acc[s+3]*(1.f/128.f) : 0.f;
        *(float4*)(op + s) = v;
    }
}

// ---------------------------------------------------------------------------
// Pointwise weight prep (hi/lo bf16 B-fragment slabs), remap for padded concat.
// ---------------------------------------------------------------------------
__global__ void prep_pw(const float* __restrict__ src, short* __restrict__ dh,
                        short* __restrict__ dl, int K, int N, int NP, int total,
                        int remap)
{
    int idx = blockIdx.x*256 + threadIdx.x;
    if(idx >= total) return;
    int j  = idx & 7;
    int n  = (idx>>3) % NP;
    int k8 = (idx>>3) / NP;
    int k  = k8*8 + j;
    if(remap) k = (k < 81) ? k : ((k < 96) ? -1 : k - 15);
    float v = (k>=0 && k<K && n<N) ? src[(size_t)k*N + n] : 0.f;
    short h = bf16h(v);
    dh[idx] = h;
    dl[idx] = bf16h(v - bf16f(h));
}

// Depthwise weight prep: [9][K0] slab, remapped/zero-padded.
__global__ void prep_dw(const float* __restrict__ src, float* __restrict__ dst,
                        int K, int K0, int remap, int total)
{
    int idx = blockIdx.x*256 + threadIdx.x;
    if(idx >= total) return;
    int k = idx / K0, c = idx - k*K0;
    int cr = c;
    if(remap) cr = (c < 81) ? c : ((c < 96) ? -1 : c - 15);
    dst[idx] = (cr>=0 && cr<K) ? src[k*K + cr] : 0.f;
}

// ---------------------------------------------------------------------------
// Fused depthwise-3x3 (fp32 VALU) + pointwise-1x1 (split-bf16 MFMA, fp32 acc).
// Tile 16x8 px, 4 waves 2(m)x2(n).  K-chunks of 32, double-buffered DMA
// staging; chunk k+1's DMA issued after chunk k's opening barrier (overlaps
// depthwise+MFMA of chunk k); lgkm-only mid barrier keeps the prefetch
// in flight through the MFMA phase.
//
// Depthwise work grouping: one thread = 4 horizontally-consecutive px x 4 ch.
// The 3x3 window over 4 px spans 3 rows x 6 cols -> 18 xv reads (was 36) and
// 9 weight reads (was 36) per chunk.  dsh slab stride = DSLAB=1032 shorts so
// the hi/lo b64 writes land on 16 distinct bank-pair columns per 16 lanes.
// ---------------------------------------------------------------------------
template<int CINR,int K0,int COUT,int NP,bool BIAS,bool ACT,bool CONCAT>
__global__ __launch_bounds__(256,2) void sep_mfma(
    const float* __restrict__ xin, const float* __restrict__ cost,
    const float* __restrict__ prv, const float* __restrict__ nxt,
    const float* __restrict__ dwp, const short* __restrict__ wh,
    const short* __restrict__ wl, const float* __restrict__ bias,
    const float* __restrict__ zb, float* __restrict__ out)
{
    constexpr int TN = NP/32;           // n-tiles per wave (16 couts each)
    __shared__ float xs[2][180*36];     // halo 10(y) x 18(x), stride 36
    __shared__ short dshh[4*DSLAB];     // [k8][px][j]  hi
    __shared__ short dshl[4*DSLAB];     // [k8][px][j]  lo
    __shared__ float dwls[2][9*32];

    const int tid = threadIdx.x;
    const int x0 = blockIdx.x*16, y0 = blockIdx.y*8, b = blockIdx.z;
    const int lane = tid & 63;
    const int wv   = tid >> 6;
    const int wm   = wv >> 1, wn = wv & 1;
    const int l15  = lane & 15, quad = lane >> 4;

    f32x4 acc[4][TN];
#pragma unroll
    for(int i=0;i<4;i++)
#pragma unroll
        for(int nt=0;nt<TN;nt++) acc[i][nt] = (f32x4){0.f,0.f,0.f,0.f};

    auto stage = [&](int c0, int pb){
        if(tid < 72)
            gld16(&dwls[pb][(tid>>3)*32 + (tid&7)*4],
                  dwp + (tid>>3)*K0 + c0 + (tid&7)*4);
        const float* src; int str, coff;
        if(CONCAT){
            if(c0 < 96)      { src = cost; str = NSP; coff = c0; }
            else if(c0 < 224){ src = prv;  str = 128; coff = c0-96; }
            else             { src = nxt;  str = 128; coff = c0-224; }
        } else { src = xin; str = CINR; coff = c0; }
        const float* sb = src + (size_t)b*HH*WW*str + coff;
        float* xp = &xs[pb][0];
#pragma unroll
        for(int it=0;it<7;it++){
            int e = it*256 + tid;
            if(e < 1620){                               // prefix mask only
                int hp = e/9, q = e - hp*9;
                int hy = y0-1 + hp/18, hx = x0-1 + hp%18;
                bool ok = (q < 8) && hy>=0 && hy<HH && hx>=0 && hx<WW;
                const float* gp = ok ? (sb + ((size_t)hy*WW + hx)*str + q*4)
                                     : zb;
                gld16(xp + hp*36 + q*4, gp);
            }
        }
    };

    // depthwise work identity: 4 consecutive px (same row), 4 channels
    const int c4  = tid & 7;           // channel quartet 0..7
    const int pxg = tid >> 3;          // pixel group 0..31
    const int dpy = pxg >> 2;          // tile row 0..7
    const int dxb = (pxg & 3) * 4;     // tile col base 0,4,8,12

    stage(0, 0);
    int pb = 0;
    for(int c0=0;c0<K0;c0+=32){
        __syncthreads();   // drains this chunk's DMA (issued last iteration)
        // ---- B fragments for this chunk (issued before prefetch DMA) ----
        const int k8 = (c0>>3) + quad;
        short8 Bh[TN], Bl[TN];
#pragma unroll
        for(int nt=0;nt<TN;nt++){
            int n = wn*(NP/2) + nt*16 + l15;
            size_t off = ((size_t)k8*NP + n)*8;
            Bh[nt] = *(const short8*)(wh + off);
            Bl[nt] = *(const short8*)(wl + off);
        }
        // ---- prefetch next chunk into the other buffer ----
        if(c0+32 < K0) stage(c0+32, pb^1);
        // ---- depthwise 3x3: 4 px x 4 ch per thread, sliding 6-col window ----
        const float* xp = &xs[pb][0];
        const float* dwc = &dwls[pb][0];
        {
            float4 o[4];
#pragma unroll
            for(int dx=0;dx<4;dx++) o[dx] = make_float4(0.f,0.f,0.f,0.f);
#pragma unroll
            for(int kh=0;kh<3;kh++){
                float4 xw[6];
#pragma unroll
                for(int t=0;t<6;t++)
                    xw[t] = *(const float4*)&xp[((dpy+kh)*18 + dxb + t)*36 + c4*4];
#pragma unroll
                for(int kw=0;kw<3;kw++){
                    float4 w4 = *(const float4*)&dwc[(kh*3+kw)*32 + c4*4];
#pragma unroll
                    for(int dx=0;dx<4;dx++){
                        float4 xv = xw[kw+dx];
                        o[dx].x = fmaf(xv.x,w4.x,o[dx].x);
                        o[dx].y = fmaf(xv.y,w4.y,o[dx].y);
                        o[dx].z = fmaf(xv.z,w4.z,o[dx].z);
                        o[dx].w = fmaf(xv.w,w4.w,o[dx].w);
                    }
                }
            }
            const int wbase = (c4>>1)*DSLAB + (pxg*4)*8 + (c4&1)*4;
#pragma unroll
            for(int dx=0;dx<4;dx++){
                float4 s = o[dx];
                short h0=bf16h(s.x), h1=bf16h(s.y), h2=bf16h(s.z), h3=bf16h(s.w);
                short l0=bf16h(s.x-bf16f(h0)), l1=bf16h(s.y-bf16f(h1));
                short l2=bf16h(s.z-bf16f(h2)), l3=bf16h(s.w-bf16f(h3));
                *(short4*)&dshh[wbase + dx*8] = make_short4(h0,h1,h2,h3);
                *(short4*)&dshl[wbase + dx*8] = make_short4(l0,l1,l2,l3);
            }
        }
        lds_barrier();     // orders dsh writes/reads; DMA keeps flying
        // ---- MFMA: A from LDS, B from registers ----
#pragma unroll
        for(int i=0;i<4;i++){
            int ab = quad*DSLAB + (wm*64 + i*16 + l15)*8;
            short8 Ah = *(const short8*)&dshh[ab];
            short8 Al = *(const short8*)&dshl[ab];
#pragma unroll
            for(int nt=0;nt<TN;nt++){
                f32x4 c = acc[i][nt];
                c = __builtin_amdgcn_mfma_f32_16x16x32_bf16(Ah,Bh[nt],c,0,0,0);
                c = __builtin_amdgcn_mfma_f32_16x16x32_bf16(Al,Bh[nt],c,0,0,0);
                c = __builtin_amdgcn_mfma_f32_16x16x32_bf16(Ah,Bl[nt],c,0,0,0);
                acc[i][nt] = c;
            }
        }
        lds_barrier();     // dsh reads done before next chunk's dw writes
        pb ^= 1;
    }
    // ---- epilogue: bias + mish + store ----
#pragma unroll
    for(int i=0;i<4;i++){
        int pxb = wm*64 + i*16 + quad*4;
#pragma unroll
        for(int nt=0;nt<TN;nt++){
            int cout = wn*(NP/2) + nt*16 + l15;
            if(cout < COUT){
                float bv = BIAS ? bias[cout] : 0.f;
#pragma unroll
                for(int r=0;r<4;r++){
                    int p = pxb + r;
                    int y = y0 + (p>>4), x = x0 + (p&15);
                    float v = acc[i][nt][r] + bv;
                    if(ACT) v = mish_f(v);
                    out[(((size_t)b*HH + y)*WW + x)*COUT + cout] = v;
                }
            }
        }
    }
}

// ---------------------------------------------------------------------------
extern "C" void kernel_launch(void* const* d_in, const int* in_sizes, int n_in,
                              void* d_out, int out_size, void* d_ws, size_t ws_size,
                              hipStream_t stream)
{
    (void)in_sizes; (void)n_in; (void)out_size;
    const float* prv = (const float*)d_in[0];
    const float* nxt = (const float*)d_in[1];
    const float* dws[6] = {(const float*)d_in[2],(const float*)d_in[5],(const float*)d_in[8],
                           (const float*)d_in[11],(const float*)d_in[14],(const float*)d_in[17]};
    const float* pws[6] = {(const float*)d_in[3],(const float*)d_in[6],(const float*)d_in[9],
                           (const float*)d_in[12],(const float*)d_in[15],(const float*)d_in[18]};
    const float* b0  = (const float*)d_in[4];
    const float* b1  = (const float*)d_in[7];
    const float* b2  = (const float*)d_in[10];
    const float* b3  = (const float*)d_in[13];
    const float* b4  = (const float*)d_in[16];

    // ---- weight slabs: pw hi/lo bf16 + dw fp32 [9][K0] + zero scratch ----
    const int   Ks[6]   = {337,128,128, 96, 64, 32};
    const int   K0s[6]  = {352,128,128, 96, 64, 32};
    const int   Ns[6]   = {128,128, 96, 64, 32,  2};
    const int   NPs[6]  = {128,128, 96, 64, 32, 32};
    const int   rmp[6]  = {  1,  0,  0,  0,  0,  0};
    size_t offs[6]; size_t E = 0;
    for(int i=0;i<6;i++){ offs[i] = E; E += (size_t)K0s[i]*NPs[i]; }
    size_t dwoffs[6]; size_t Edw = 0;
    for(int i=0;i<6;i++){ dwoffs[i] = Edw; Edw += (size_t)9*K0s[i]; }

    short* Whs = (short*)d_ws;
    short* Wls = Whs + E;
    float* Dwp = (float*)((char*)d_ws + ((E*2*sizeof(short) + 255) & ~(size_t)255));
    float* Zb  = Dwp + Edw;                    // 64-float zero scratch
    size_t wbytes = (((char*)(Zb + 64) - (char*)d_ws) + 255) & ~(size_t)255;

    zero_k<<<1,64,0,stream>>>(Zb, 64);
    for(int i=0;i<6;i++){
        int total = K0s[i]*NPs[i];
        prep_pw<<<(total+255)/256,256,0,stream>>>(pws[i], Whs+offs[i], Wls+offs[i],
                                                  Ks[i], Ns[i], NPs[i], total, rmp[i]);
        int tdw = 9*K0s[i];
        prep_dw<<<(tdw+255)/256,256,0,stream>>>(dws[i], Dwp+dwoffs[i],
                                                Ks[i], K0s[i], rmp[i], tdw);
    }

    // ---- activation buffers, batch-chunked ----
    const size_t per_batch_floats = (size_t)HWPIX * (NSP + 128 + 128);
    size_t avail = (ws_size > wbytes) ? (ws_size - wbytes) : 0;
    int NB = (int)(avail / (per_batch_floats * sizeof(float)));
    if(NB > BATCH) NB = BATCH;
    if(NB < 1)     NB = 1;
    while(BATCH % NB) NB--;

    float* fbase = (float*)((char*)d_ws + wbytes);
    float* costb = fbase;
    float* bufA  = costb + (size_t)NB*HWPIX*NSP;
    float* bufB  = bufA  + (size_t)NB*HWPIX*128;

    for(int bb=0; bb<BATCH; bb+=NB){
        const float* prv_o = prv + (size_t)bb*HWPIX*CC;
        const float* nxt_o = nxt + (size_t)bb*HWPIX*CC;
        float*       out_o = (float*)d_out + (size_t)bb*HWPIX*2;
        dim3 gc(WW/16, HH/16, NB);
        dim3 gs(WW/16, HH/8,  NB);

        cost_kernel<<<gc,256,0,stream>>>(prv_o, nxt_o, Zb, costb);
        sep_mfma<337,352,128,128,true ,true ,true ><<<gs,256,0,stream>>>(nullptr, costb, prv_o, nxt_o, Dwp+dwoffs[0], Whs+offs[0], Wls+offs[0], b0, Zb, bufA);
        sep_mfma<128,128,128,128,true ,true ,false><<<gs,256,0,stream>>>(bufA, nullptr,nullptr,nullptr, Dwp+dwoffs[1], Whs+offs[1], Wls+offs[1], b1, Zb, bufB);
        sep_mfma<128,128, 96, 96,true ,true ,false><<<gs,256,0,stream>>>(bufB, nullptr,nullptr,nullptr, Dwp+dwoffs[2], Whs+offs[2], Wls+offs[2], b2, Zb, bufA);
        sep_mfma< 96, 96, 64, 64,true ,true ,false><<<gs,256,0,stream>>>(bufA, nullptr,nullptr,nullptr, Dwp+dwoffs[3], Whs+offs[3], Wls+offs[3], b3, Zb, bufB);
        sep_mfma< 64, 64, 32, 32,true ,true ,false><<<gs,256,0,stream>>>(bufB, nullptr,nullptr,nullptr, Dwp+dwoffs[4], Whs+offs[4], Wls+offs[4], b4, Zb, bufA);
        sep_mfma< 32, 32,  2, 32,false,false,false><<<gs,256,0,stream>>>(bufA, nullptr,nullptr,nullptr, Dwp+dwoffs[5], Whs+offs[5], Wls+offs[5], nullptr, Zb, out_o);
    }
}